// Round 7
// baseline (1703.392 us; speedup 1.0000x reference)
//
#include <hip/hip_runtime.h>

// ResidualVQ on MI355X (gfx950). ROUND 11: de-stage the codebook (no LDS B).
// z: [65536,256] f32; codebooks: [4,1024,256] f32.
// Outputs (flat f32): z_q [65536*256], codes-as-float [65536*4], loss [1].
//
// R4-R10 accounting: MFMA-busy pinned at the ~165us floor in EVERY round;
// the other ~1000us is synchronization around L2-resident data. The
// per-level split codebook (hi+lo = 1MB) fits each XCD's 4MB L2, yet we
// paid 128-256 barrier crossings per block to stage it through LDS
// (Common-mistake #7: staging cache-fit data). R10 proved no-spill needs
// VGPR~236 (launch_bounds(256,1)); R6/R10 A/B proved phase count and
// barriers dominate. R11: screen loop reads B-fragments DIRECTLY from
// global (global_load_dwordx4, same bytes the DMA staged) -> zero
// barriers, zero vmcnt, zero swizzle, LDS = 11.7KB metadata only.
// Load latency hides under each chunk's 48-MFMA ladder; 2 waves/SIMD
// co-schedule. Numerics bit-identical: same values, same MFMA order,
// same top-2/merge/rescan/epilogue (harness-verified R6/R10).

#define NB 65536
#define ND 256
#define NK 1024
#define NL 4
#define MROWS 128
#define NBLK (NB / MROWS)      // 512
#define CHUNK 16               // codes per screen iteration
#define NCH (NK / CHUNK)       // 64
#define FLAG_MARGIN 1e-3f

typedef __attribute__((ext_vector_type(8))) short short8;
typedef __attribute__((ext_vector_type(4))) float f32x4;

#define MFMA __builtin_amdgcn_mfma_f32_16x16x32_bf16

__device__ inline unsigned short f2bf(float x) {
  unsigned u = __float_as_uint(x);
  u = u + 0x7FFFu + ((u >> 16) & 1u);        // RNE to bf16 (inputs are finite)
  return (unsigned short)(u >> 16);
}
__device__ inline float bf2f(unsigned short h) {
  return __uint_as_float(((unsigned)h) << 16);
}

// ---- numpy-bit-exact fp32 kernels (R3-proven) ----
__device__ float np_sum256_sq(const float* __restrict__ a) {
#pragma clang fp contract(off)
  float out[2];
  for (int h = 0; h < 2; ++h) {
    const float* p = a + 128 * h;
    float r[8];
    for (int j = 0; j < 8; ++j) r[j] = p[j] * p[j];
    for (int i = 8; i < 128; i += 8)
      for (int j = 0; j < 8; ++j) r[j] += p[i + j] * p[i + j];
    out[h] = ((r[0] + r[1]) + (r[2] + r[3])) + ((r[4] + r[5]) + (r[6] + r[7]));
  }
  return out[0] + out[1];
}
__device__ float np_einsum256(const float* __restrict__ r,
                              const float* __restrict__ c) {
#pragma clang fp contract(off)
  float e[4] = {0.f, 0.f, 0.f, 0.f};
  for (int d = 0; d < 256; d += 4) {
    e[0] += r[d + 0] * c[d + 0];
    e[1] += r[d + 1] * c[d + 1];
    e[2] += r[d + 2] * c[d + 2];
    e[3] += r[d + 3] * c[d + 3];
  }
  return (e[0] + e[1]) + (e[2] + e[3]);
}
__device__ float np_dist(const float* __restrict__ resrow,
                         const float* __restrict__ crow, float r2) {
#pragma clang fp contract(off)
  float E = np_einsum256(resrow, crow);
  float c2 = np_sum256_sq(crow);
  float t1 = r2 - 2.0f * E;
  return t1 + c2;
}

// ---- prep: split codebook into bf16 hi/lo, compute c2 ----
__global__ void prep_split(const float* __restrict__ cb,
                           unsigned short* __restrict__ whi,
                           unsigned short* __restrict__ wlo) {
  int i = blockIdx.x * 256 + threadIdx.x;   // 4096 blocks cover 1,048,576
  float c = cb[i];
  unsigned short h = f2bf(c);
  whi[i] = h;
  wlo[i] = f2bf(c - bf2f(h));
}
__global__ void prep_c2(const float* __restrict__ cb, float* __restrict__ c2) {
  int k = blockIdx.x;                        // 4096 codes total
  int lane = threadIdx.x;                    // 64
  const float* p = cb + (size_t)k * ND + lane * 4;
  double s = (double)p[0]*p[0] + (double)p[1]*p[1]
           + (double)p[2]*p[2] + (double)p[3]*p[3];
  for (int off = 32; off >= 1; off >>= 1) s += __shfl_down(s, off);
  if (lane == 0) c2[k] = (float)s;
}

// LDS map (11776 B):
//  c2s:  @0     4096   float[1024]
//  selh: @4096  2048   int[128*4]
//  flags:@6144  512    int[128]
//  resr: @6656  1024   rescan residual (256 f32)
//  redf: @7680  1024   f32[256]
//  redk: @8704  1024   int[256]
//  lred: @9728  2048   double[256] loss reduction

__global__ __launch_bounds__(256, 1)
void rvq_main(const float* __restrict__ z, const float* __restrict__ cbf,
              const unsigned short* __restrict__ whi,
              const unsigned short* __restrict__ wlo,
              const float* __restrict__ c2w, float* __restrict__ out) {
  extern __shared__ char smem[];
  float* c2s  = (float*)smem;
  int*   selh = (int*)(smem + 4096);
  int*   flags= (int*)(smem + 6144);
  float* resr = (float*)(smem + 6656);
  float* redf = (float*)(smem + 7680);
  int*   redk = (int*)(smem + 8704);
  double* lred= (double*)(smem + 9728);

  const int tid  = threadIdx.x;
  const int wave = tid >> 6, lane = tid & 63;
  const int quad = lane >> 4, lx = lane & 15;
  const int blk  = blockIdx.x;

  for (int lvl = 0; lvl < NL; ++lvl) {
    __syncthreads();   // selh stable from prev level; c2s/overlays free
    // ---- stage c2 for this level ----
#pragma unroll
    for (int t = 0; t < 4; ++t)
      c2s[t * 256 + tid] = c2w[lvl * NK + t * 256 + tid];

    // ---- build A-fragments (register-resident, 32 rows/wave) ----
    short8 Ah[2][8], Al[2][8];
#pragma unroll
    for (int s = 0; s < 2; ++s) {
      const int rloc = wave * 32 + s * 16 + lx;
      const size_t rg = (size_t)(blk * MROWS + rloc);
#pragma unroll
      for (int ks = 0; ks < 8; ++ks) {
        const int k0 = 32 * ks + quad * 8;
        const float* zp = z + rg * ND + k0;
        float4 p0 = *(const float4*)zp;
        float4 p1 = *(const float4*)(zp + 4);
        for (int l = 0; l < lvl; ++l) {
          int sel = selh[rloc * 4 + l];
          const float* cp = cbf + (size_t)(l * NK + sel) * ND + k0;
          float4 q0 = *(const float4*)cp, q1 = *(const float4*)(cp + 4);
          p0.x -= q0.x; p0.y -= q0.y; p0.z -= q0.z; p0.w -= q0.w;
          p1.x -= q1.x; p1.y -= q1.y; p1.z -= q1.z; p1.w -= q1.w;
        }
        float v0[8] = {p0.x, p0.y, p0.z, p0.w, p1.x, p1.y, p1.z, p1.w};
#pragma unroll
        for (int j = 0; j < 8; ++j) {
          unsigned short h = f2bf(v0[j]);
          Ah[s][ks][j] = (short)h;
          Al[s][ks][j] = (short)f2bf(v0[j] - bf2f(h));
        }
      }
    }

    // ---- screen: per-lane top-2 over 8 (stripe,reg) streams ----
    float m1[8], m2[8]; int i1[8];
#pragma unroll
    for (int t = 0; t < 8; ++t) { m1[t] = 1e30f; m2[t] = 1e30f; i1[t] = 0; }

    __syncthreads();   // c2s visible to all waves

    // B-fragments straight from global (L2-resident: 1MB/level/XCD).
    // Per chunk: lane (lx,quad) reads code row (ch*16+lx), k-slice
    // [32ks+8quad .. +8) from whi/wlo — identical bytes the old DMA
    // staged, identical MFMA order -> bit-identical accumulators.
    const unsigned short* hrow = whi + (size_t)lvl * NK * ND
                                 + (size_t)lx * ND + quad * 8;
    const unsigned short* lrow = wlo + (size_t)lvl * NK * ND
                                 + (size_t)lx * ND + quad * 8;

#pragma unroll 1
    for (int ch = 0; ch < NCH; ++ch) {
      const unsigned short* hb = hrow + (size_t)ch * CHUNK * ND;
      const unsigned short* lb = lrow + (size_t)ch * CHUNK * ND;
      short8 bh[8], bl[8];
#pragma unroll
      for (int ks = 0; ks < 8; ++ks) {
        bh[ks] = *(const short8*)(hb + ks * 32);
        bl[ks] = *(const short8*)(lb + ks * 32);
      }
      f32x4 a0a = {0,0,0,0}, a0b = {0,0,0,0}, a1a = {0,0,0,0}, a1b = {0,0,0,0};
      __builtin_amdgcn_s_setprio(1);                // T5: favor MFMA region
#pragma unroll
      for (int ks = 0; ks < 8; ks += 2) {
        short8 vb0 = bh[ks],     wb0 = bl[ks];
        short8 vb1 = bh[ks + 1], wb1 = bl[ks + 1];
        a0a = MFMA(Ah[0][ks], vb0, a0a, 0, 0, 0);
        a1a = MFMA(Ah[1][ks], vb0, a1a, 0, 0, 0);
        a0a = MFMA(Al[0][ks], vb0, a0a, 0, 0, 0);
        a1a = MFMA(Al[1][ks], vb0, a1a, 0, 0, 0);
        a0a = MFMA(Ah[0][ks], wb0, a0a, 0, 0, 0);
        a1a = MFMA(Ah[1][ks], wb0, a1a, 0, 0, 0);
        a0b = MFMA(Ah[0][ks + 1], vb1, a0b, 0, 0, 0);
        a1b = MFMA(Ah[1][ks + 1], vb1, a1b, 0, 0, 0);
        a0b = MFMA(Al[0][ks + 1], vb1, a0b, 0, 0, 0);
        a1b = MFMA(Al[1][ks + 1], vb1, a1b, 0, 0, 0);
        a0b = MFMA(Ah[0][ks + 1], wb1, a0b, 0, 0, 0);
        a1b = MFMA(Ah[1][ks + 1], wb1, a1b, 0, 0, 0);
      }
      __builtin_amdgcn_s_setprio(0);
      const int kidx = ch * CHUNK + lx;
      const float c2v = c2s[kidx];
#pragma unroll
      for (int s = 0; s < 2; ++s)
#pragma unroll
        for (int r = 0; r < 4; ++r) {
          float e = (s == 0) ? (a0a[r] + a0b[r]) : (a1a[r] + a1b[r]);
          float d = fmaf(-2.0f, e, c2v);
          int st = s * 4 + r;
          if (d < m1[st]) { m2[st] = m1[st]; m1[st] = d; i1[st] = kidx; }
          else if (d < m2[st]) m2[st] = d;
        }
    }

    // ---- cross-lane top-2 merge: butterfly over the 16-lane lx group ----
    int myflag = 0;
#pragma unroll
    for (int t = 0; t < 8; ++t) {
      float a1 = m1[t], a2 = m2[t]; int ai = i1[t];
#pragma unroll
      for (int off = 1; off < 16; off <<= 1) {
        float o1 = __shfl_xor(a1, off);
        float o2 = __shfl_xor(a2, off);
        int   oi = __shfl_xor(ai, off);
        if (o1 < a1 || (o1 == a1 && oi < ai)) {
          a2 = fminf(a1, o2); a1 = o1; ai = oi;
        } else {
          a2 = fminf(a2, o1);
        }
      }
      if (lx == 0) {
        int rloc = wave * 32 + (t >> 2) * 16 + quad * 4 + (t & 3);
        selh[rloc * 4 + lvl] = ai;
        int f = (a2 - a1 <= FLAG_MARGIN) ? 1 : 0;
        flags[rloc] = f;
        myflag |= f;
      }
    }
    int anyf = __syncthreads_or(myflag);

    // ---- numpy-bit-exact full-K rescan of flagged rows (~0.1%) ----
    if (anyf) {
      for (int r = 0; r < MROWS; ++r) {
        if (flags[r]) {
          {
            float v = z[(size_t)(blk * MROWS + r) * ND + tid];
            for (int l = 0; l < lvl; ++l)
              v -= cbf[(size_t)(l * NK + selh[r * 4 + l]) * ND + tid];
            resr[tid] = v;
          }
          __syncthreads();
          float r2 = np_sum256_sq(resr);
          float bd = 1e30f; int bk = 0x7fffffff;
          for (int u = 0; u < 4; ++u) {
            int k = u * 256 + tid;
            float dd = np_dist(resr, cbf + (size_t)(lvl * NK + k) * ND, r2);
            if (dd < bd || (dd == bd && k < bk)) { bd = dd; bk = k; }
          }
          redf[tid] = bd; redk[tid] = bk;
          __syncthreads();
          if (tid == 0) {
            float gb = 1e30f; int gk = 0x7fffffff;
            for (int t2 = 0; t2 < 256; ++t2) {
              if (redf[t2] < gb || (redf[t2] == gb && redk[t2] < gk)) {
                gb = redf[t2]; gk = redk[t2];
              }
            }
            selh[r * 4 + lvl] = gk;
          }
          __syncthreads();
        }
      }
    }
  }

  // ---- epilogue: z_q = sum of selected codes (ref order), codes, loss ----
  __syncthreads();
  double lacc = 0.0;
#pragma unroll 1
  for (int it = 0; it < 32; ++it) {
    int i = it * 256 + tid;
    int row = i >> 6, dc = i & 63;
    size_t rg = (size_t)(blk * MROWS + row);
    float4 z4 = *(const float4*)(z + rg * ND + dc * 4);
    float4 q; q.x = 0.f; q.y = 0.f; q.z = 0.f; q.w = 0.f;
    for (int l = 0; l < NL; ++l) {
      int sel = selh[row * 4 + l];
      float4 c4 = *(const float4*)(cbf + (size_t)(l * NK + sel) * ND + dc * 4);
      q.x += c4.x; q.y += c4.y; q.z += c4.z; q.w += c4.w;
    }
    *(float4*)(out + rg * ND + dc * 4) = q;
    float dx = q.x - z4.x, dy = q.y - z4.y, dz = q.z - z4.z, dw = q.w - z4.w;
    lacc += (double)dx * dx + (double)dy * dy + (double)dz * dz + (double)dw * dw;
  }
  if (tid < MROWS) {
    for (int l = 0; l < NL; ++l)
      out[(size_t)NB * ND + (size_t)(blk * MROWS + tid) * NL + l] =
          (float)selh[tid * 4 + l];
  }
  __syncthreads();
  lred[tid] = lacc;
  __syncthreads();
  if (tid == 0) {
    double s = 0.0;
    for (int t = 0; t < 256; ++t) s += lred[t];
    atomicAdd(out + (size_t)NB * ND + (size_t)NB * NL,
              (float)(s / ((double)NB * (double)ND)));
  }
}

extern "C" void kernel_launch(void* const* d_in, const int* in_sizes, int n_in,
                              void* d_out, int out_size, void* d_ws, size_t ws_size,
                              hipStream_t stream) {
  const float* z  = (const float*)d_in[0];
  const float* cb = (const float*)d_in[1];
  float* out = (float*)d_out;

  unsigned short* whi = (unsigned short*)d_ws;                 // 2 MB
  unsigned short* wlo = whi + (size_t)NL * NK * ND;            // 2 MB
  float* c2w = (float*)(wlo + (size_t)NL * NK * ND);           // 16 KB

  // zero the loss slot (harness poisons d_out with 0xAA)
  hipMemsetAsync((void*)(out + (size_t)NB * ND + (size_t)NB * NL), 0,
                 sizeof(float), stream);

  prep_split<<<dim3(4096), dim3(256), 0, stream>>>(cb, whi, wlo);
  prep_c2<<<dim3(4096), dim3(64), 0, stream>>>(cb, c2w);

  const size_t shmem = 11776;
  hipFuncSetAttribute((const void*)rvq_main,
                      hipFuncAttributeMaxDynamicSharedMemorySize, (int)shmem);
  rvq_main<<<dim3(NBLK), dim3(256), shmem, stream>>>(z, cb, whi, wlo, c2w, out);
}

// Round 8
// 1568.788 us; speedup vs baseline: 1.0858x; 1.0858x over previous
//
#include <hip/hip_runtime.h>

// ResidualVQ on MI355X (gfx950). ROUND 12: R6 structure, uncapped VGPRs.
// z: [65536,256] f32; codebooks: [4,1024,256] f32.
// Outputs (flat f32): z_q [65536*256], codes-as-float [65536*4], loss [1].
//
// Ladder: R6 (CHUNK=32 DMA pipeline, VGPR capped 128 -> ~108 regs spilled,
// 334MB scratch writes) = 1135us = best. R10 (CHUNK=16 no-spill) = 1535
// confounded phase-count with spill. R11 (no LDS, direct L2) = 1703:
// 4x redundant L2 reads at 50% line utilization lose to staging.
// VGPR-cap map measured: bounds arg1->256, 2->128, 3->84, 4->64.
// KEY: at VGPR~236, occupancy = 2 waves/SIMD = 8 waves/CU = 2 blocks -
// IDENTICAL to R6's LDS-capped occupancy. Removing the spill is free.
// R12 = R6 verbatim, bounds(256,2)->(256,1). Single-variable experiment:
// removes ~270MB x2 scratch round-trip from the hot loop at fixed
// occupancy and phase structure. Numerics identical (harness-verified).

#define NB 65536
#define ND 256
#define NK 1024
#define NL 4
#define MROWS 128
#define NBLK (NB / MROWS)      // 512
#define CHUNK 32               // codes per LDS chunk (double-buffered)
#define NCH (NK / CHUNK)       // 32
#define FLAG_MARGIN 1e-3f

typedef __attribute__((ext_vector_type(8))) short short8;
typedef __attribute__((ext_vector_type(4))) float f32x4;
typedef const __attribute__((address_space(1))) unsigned int gu32;
typedef __attribute__((address_space(3))) unsigned int lu32;

#define MFMA __builtin_amdgcn_mfma_f32_16x16x32_bf16

__device__ inline unsigned short f2bf(float x) {
  unsigned u = __float_as_uint(x);
  u = u + 0x7FFFu + ((u >> 16) & 1u);        // RNE to bf16 (inputs are finite)
  return (unsigned short)(u >> 16);
}
__device__ inline float bf2f(unsigned short h) {
  return __uint_as_float(((unsigned)h) << 16);
}

// ---- numpy-bit-exact fp32 kernels (R3-proven) ----
__device__ float np_sum256_sq(const float* __restrict__ a) {
#pragma clang fp contract(off)
  float out[2];
  for (int h = 0; h < 2; ++h) {
    const float* p = a + 128 * h;
    float r[8];
    for (int j = 0; j < 8; ++j) r[j] = p[j] * p[j];
    for (int i = 8; i < 128; i += 8)
      for (int j = 0; j < 8; ++j) r[j] += p[i + j] * p[i + j];
    out[h] = ((r[0] + r[1]) + (r[2] + r[3])) + ((r[4] + r[5]) + (r[6] + r[7]));
  }
  return out[0] + out[1];
}
__device__ float np_einsum256(const float* __restrict__ r,
                              const float* __restrict__ c) {
#pragma clang fp contract(off)
  float e[4] = {0.f, 0.f, 0.f, 0.f};
  for (int d = 0; d < 256; d += 4) {
    e[0] += r[d + 0] * c[d + 0];
    e[1] += r[d + 1] * c[d + 1];
    e[2] += r[d + 2] * c[d + 2];
    e[3] += r[d + 3] * c[d + 3];
  }
  return (e[0] + e[1]) + (e[2] + e[3]);
}
__device__ float np_dist(const float* __restrict__ resrow,
                         const float* __restrict__ crow, float r2) {
#pragma clang fp contract(off)
  float E = np_einsum256(resrow, crow);
  float c2 = np_sum256_sq(crow);
  float t1 = r2 - 2.0f * E;
  return t1 + c2;
}

// ---- prep: split codebook into bf16 hi/lo, compute c2 ----
__global__ void prep_split(const float* __restrict__ cb,
                           unsigned short* __restrict__ whi,
                           unsigned short* __restrict__ wlo) {
  int i = blockIdx.x * 256 + threadIdx.x;   // 4096 blocks cover 1,048,576
  float c = cb[i];
  unsigned short h = f2bf(c);
  whi[i] = h;
  wlo[i] = f2bf(c - bf2f(h));
}
__global__ void prep_c2(const float* __restrict__ cb, float* __restrict__ c2) {
  int k = blockIdx.x;                        // 4096 codes total
  int lane = threadIdx.x;                    // 64
  const float* p = cb + (size_t)k * ND + lane * 4;
  double s = (double)p[0]*p[0] + (double)p[1]*p[1]
           + (double)p[2]*p[2] + (double)p[3]*p[3];
  for (int off = 32; off >= 1; off >>= 1) s += __shfl_down(s, off);
  if (lane == 0) c2[k] = (float)s;
}

// LDS map (72192 B):
//  bufA: @0      32768  (hi rows 0..31 x 512B @0; lo @16384) XOR-swizzled
//  bufB: @32768  32768
//  c2s:  @65536  4096   float[1024]
//  selh: @69632  2048   int[128*4]
//  flags:@71680  512    int[128]
// overlays inside bufA (phase-disjoint, DMA drained, barrier-separated):
//  resr: @0      1024   rescan residual
//  redf: @1024   1024
//  redk: @2048   1024
//  lred: @0      2048   loss reduction (epilogue)

// DMA one 32-code chunk (hi+lo) into a 32KB buffer. 8 instrs/wave, 32 total.
// Linear LDS dest (wave-uniform base + lane*16); swizzle applied by
// pre-permuting the GLOBAL source column: slot scol holds gcol = scol^(row&7).
__device__ __forceinline__ void stage_chunk(
    const unsigned short* __restrict__ whi,
    const unsigned short* __restrict__ wlo,
    unsigned short* buf, int lvl, int ch, int wave, int lane) {
  const int rp = lane >> 5;          // row within the instr's row-pair
  const int scol = lane & 31;        // 16B slot within row
#pragma unroll
  for (int j = 0; j < 8; ++j) {
    const int g = wave * 8 + j;      // 0..31 instr id
    const int region = g >> 4;       // 0 = hi, 1 = lo
    const int gi = g & 15;           // row-pair index
    const int row = gi * 2 + rp;     // 0..31 code row in chunk
    const int gcol = scol ^ (row & 7);
    const unsigned short* src = (region ? wlo : whi)
        + (size_t)lvl * NK * ND + (size_t)(ch * CHUNK + row) * ND + gcol * 8;
    char* dst = (char*)buf + region * 16384 + gi * 1024;   // wave-uniform
    __builtin_amdgcn_global_load_lds((gu32*)src, (lu32*)dst, 16, 0, 0);
  }
}

__global__ __launch_bounds__(256, 1)
void rvq_main(const float* __restrict__ z, const float* __restrict__ cbf,
              const unsigned short* __restrict__ whi,
              const unsigned short* __restrict__ wlo,
              const float* __restrict__ c2w, float* __restrict__ out) {
  extern __shared__ char smem[];
  unsigned short* bufA = (unsigned short*)smem;
  unsigned short* bufB = (unsigned short*)(smem + 32768);
  float* c2s  = (float*)(smem + 65536);
  int*   selh = (int*)(smem + 69632);
  int*   flags= (int*)(smem + 71680);
  float* resr = (float*)smem;
  float* redf = (float*)(smem + 1024);
  int*   redk = (int*)(smem + 2048);
  double* lred= (double*)smem;

  const int tid  = threadIdx.x;
  const int wave = tid >> 6, lane = tid & 63;
  const int quad = lane >> 4, lx = lane & 15;
  const int blk  = blockIdx.x;

  for (int lvl = 0; lvl < NL; ++lvl) {
    __syncthreads();   // selh stable from prev level; overlays free
    // ---- stage c2 for this level ----
#pragma unroll
    for (int t = 0; t < 4; ++t)
      c2s[t * 256 + tid] = c2w[lvl * NK + t * 256 + tid];

    // ---- build A-fragments (register-resident, 32 rows/wave) ----
    short8 Ah[2][8], Al[2][8];
#pragma unroll
    for (int s = 0; s < 2; ++s) {
      const int rloc = wave * 32 + s * 16 + lx;
      const size_t rg = (size_t)(blk * MROWS + rloc);
#pragma unroll
      for (int ks = 0; ks < 8; ++ks) {
        const int k0 = 32 * ks + quad * 8;
        const float* zp = z + rg * ND + k0;
        float4 p0 = *(const float4*)zp;
        float4 p1 = *(const float4*)(zp + 4);
        for (int l = 0; l < lvl; ++l) {
          int sel = selh[rloc * 4 + l];
          const float* cp = cbf + (size_t)(l * NK + sel) * ND + k0;
          float4 q0 = *(const float4*)cp, q1 = *(const float4*)(cp + 4);
          p0.x -= q0.x; p0.y -= q0.y; p0.z -= q0.z; p0.w -= q0.w;
          p1.x -= q1.x; p1.y -= q1.y; p1.z -= q1.z; p1.w -= q1.w;
        }
        float v0[8] = {p0.x, p0.y, p0.z, p0.w, p1.x, p1.y, p1.z, p1.w};
#pragma unroll
        for (int j = 0; j < 8; ++j) {
          unsigned short h = f2bf(v0[j]);
          Ah[s][ks][j] = (short)h;
          Al[s][ks][j] = (short)f2bf(v0[j] - bf2f(h));
        }
      }
    }

    // ---- screen: per-lane top-2 over 8 (stripe,reg) streams ----
    float m1[8], m2[8]; int i1[8];
#pragma unroll
    for (int t = 0; t < 8; ++t) { m1[t] = 1e30f; m2[t] = 1e30f; i1[t] = 0; }

    // c2s visible + overlays done before any DMA lands in the buffers.
    // __syncthreads drains vmcnt -> manual counting below tracks DMAs only.
    __syncthreads();
    stage_chunk(whi, wlo, bufA, lvl, 0, wave, lane);
    stage_chunk(whi, wlo, bufB, lvl, 1, wave, lane);

#pragma unroll 1
    for (int ch = 0; ch < NCH; ++ch) {
      // wait for chunk ch's 8 DMAs (keep next chunk's 8 in flight).
      if (ch + 1 < NCH) asm volatile("s_waitcnt vmcnt(8)" ::: "memory");
      else              asm volatile("s_waitcnt vmcnt(0)" ::: "memory");
      __builtin_amdgcn_s_barrier();          // raw: no vmcnt drain
      __builtin_amdgcn_sched_barrier(0);     // rule 18: pin ds_reads below
      const unsigned short* bh = (ch & 1) ? bufB : bufA;
#pragma unroll 1
      for (int tile = 0; tile < 2; ++tile) {
        f32x4 a0a = {0,0,0,0}, a0b = {0,0,0,0}, a1a = {0,0,0,0}, a1b = {0,0,0,0};
        const int crow = tile * 16 + lx;
        const unsigned short* bp = bh + crow * 256;   // 512B row stride
        const int xr = lx & 7;                        // crow & 7
        __builtin_amdgcn_s_setprio(1);                // T5: favor MFMA wave
#pragma unroll
        for (int ks = 0; ks < 8; ks += 2) {
          const int s0 = ((ks * 4 + quad) ^ xr) * 8;      // swizzled slot, hi
          const int s1 = ((ks * 4 + 4 + quad) ^ xr) * 8;  // odd ks
          short8 vb0 = *(const short8*)(bp + s0);
          short8 wb0 = *(const short8*)(bp + 8192 + s0);  // lo region +16KB
          short8 vb1 = *(const short8*)(bp + s1);
          short8 wb1 = *(const short8*)(bp + 8192 + s1);
          a0a = MFMA(Ah[0][ks], vb0, a0a, 0, 0, 0);
          a1a = MFMA(Ah[1][ks], vb0, a1a, 0, 0, 0);
          a0a = MFMA(Al[0][ks], vb0, a0a, 0, 0, 0);
          a1a = MFMA(Al[1][ks], vb0, a1a, 0, 0, 0);
          a0a = MFMA(Ah[0][ks], wb0, a0a, 0, 0, 0);
          a1a = MFMA(Ah[1][ks], wb0, a1a, 0, 0, 0);
          a0b = MFMA(Ah[0][ks + 1], vb1, a0b, 0, 0, 0);
          a1b = MFMA(Ah[1][ks + 1], vb1, a1b, 0, 0, 0);
          a0b = MFMA(Al[0][ks + 1], vb1, a0b, 0, 0, 0);
          a1b = MFMA(Al[1][ks + 1], vb1, a1b, 0, 0, 0);
          a0b = MFMA(Ah[0][ks + 1], wb1, a0b, 0, 0, 0);
          a1b = MFMA(Ah[1][ks + 1], wb1, a1b, 0, 0, 0);
        }
        __builtin_amdgcn_s_setprio(0);
        const int kidx = ch * CHUNK + crow;
        const float c2v = c2s[kidx];
#pragma unroll
        for (int s = 0; s < 2; ++s)
#pragma unroll
          for (int r = 0; r < 4; ++r) {
            float e = (s == 0) ? (a0a[r] + a0b[r]) : (a1a[r] + a1b[r]);
            float d = fmaf(-2.0f, e, c2v);
            int st = s * 4 + r;
            if (d < m1[st]) { m2[st] = m1[st]; m1[st] = d; i1[st] = kidx; }
            else if (d < m2[st]) m2[st] = d;
          }
      }
      // my LDS reads retired before anyone overwrites this buffer
      asm volatile("s_waitcnt lgkmcnt(0)" ::: "memory");
      __builtin_amdgcn_s_barrier();          // raw: all waves done reading
      __builtin_amdgcn_sched_barrier(0);     // pin prefetch DMAs below barrier
      if (ch + 2 < NCH)
        stage_chunk(whi, wlo, (ch & 1) ? bufB : bufA, lvl, ch + 2, wave, lane);
    }
    // loop exit: vmcnt==0 (last iter drained), buffers free for overlays

    // ---- cross-lane top-2 merge: butterfly over the 16-lane lx group ----
    int myflag = 0;
#pragma unroll
    for (int t = 0; t < 8; ++t) {
      float a1 = m1[t], a2 = m2[t]; int ai = i1[t];
#pragma unroll
      for (int off = 1; off < 16; off <<= 1) {
        float o1 = __shfl_xor(a1, off);
        float o2 = __shfl_xor(a2, off);
        int   oi = __shfl_xor(ai, off);
        if (o1 < a1 || (o1 == a1 && oi < ai)) {
          a2 = fminf(a1, o2); a1 = o1; ai = oi;
        } else {
          a2 = fminf(a2, o1);
        }
      }
      if (lx == 0) {
        int rloc = wave * 32 + (t >> 2) * 16 + quad * 4 + (t & 3);
        selh[rloc * 4 + lvl] = ai;
        int f = (a2 - a1 <= FLAG_MARGIN) ? 1 : 0;
        flags[rloc] = f;
        myflag |= f;
      }
    }
    int anyf = __syncthreads_or(myflag);

    // ---- numpy-bit-exact full-K rescan of flagged rows (~0.1%) ----
    if (anyf) {
      for (int r = 0; r < MROWS; ++r) {
        if (flags[r]) {
          {
            float v = z[(size_t)(blk * MROWS + r) * ND + tid];
            for (int l = 0; l < lvl; ++l)
              v -= cbf[(size_t)(l * NK + selh[r * 4 + l]) * ND + tid];
            resr[tid] = v;
          }
          __syncthreads();
          float r2 = np_sum256_sq(resr);
          float bd = 1e30f; int bk = 0x7fffffff;
          for (int u = 0; u < 4; ++u) {
            int k = u * 256 + tid;
            float dd = np_dist(resr, cbf + (size_t)(lvl * NK + k) * ND, r2);
            if (dd < bd || (dd == bd && k < bk)) { bd = dd; bk = k; }
          }
          redf[tid] = bd; redk[tid] = bk;
          __syncthreads();
          if (tid == 0) {
            float gb = 1e30f; int gk = 0x7fffffff;
            for (int t2 = 0; t2 < 256; ++t2) {
              if (redf[t2] < gb || (redf[t2] == gb && redk[t2] < gk)) {
                gb = redf[t2]; gk = redk[t2];
              }
            }
            selh[r * 4 + lvl] = gk;
          }
          __syncthreads();
        }
      }
    }
  }

  // ---- epilogue: z_q = sum of selected codes (ref order), codes, loss ----
  __syncthreads();
  double lacc = 0.0;
#pragma unroll 1
  for (int it = 0; it < 32; ++it) {
    int i = it * 256 + tid;
    int row = i >> 6, dc = i & 63;
    size_t rg = (size_t)(blk * MROWS + row);
    float4 z4 = *(const float4*)(z + rg * ND + dc * 4);
    float4 q; q.x = 0.f; q.y = 0.f; q.z = 0.f; q.w = 0.f;
    for (int l = 0; l < NL; ++l) {
      int sel = selh[row * 4 + l];
      float4 c4 = *(const float4*)(cbf + (size_t)(l * NK + sel) * ND + dc * 4);
      q.x += c4.x; q.y += c4.y; q.z += c4.z; q.w += c4.w;
    }
    *(float4*)(out + rg * ND + dc * 4) = q;
    float dx = q.x - z4.x, dy = q.y - z4.y, dz = q.z - z4.z, dw = q.w - z4.w;
    lacc += (double)dx * dx + (double)dy * dy + (double)dz * dz + (double)dw * dw;
  }
  if (tid < MROWS) {
    for (int l = 0; l < NL; ++l)
      out[(size_t)NB * ND + (size_t)(blk * MROWS + tid) * NL + l] =
          (float)selh[tid * 4 + l];
  }
  __syncthreads();
  lred[tid] = lacc;
  __syncthreads();
  if (tid == 0) {
    double s = 0.0;
    for (int t = 0; t < 256; ++t) s += lred[t];
    atomicAdd(out + (size_t)NB * ND + (size_t)NB * NL,
              (float)(s / ((double)NB * (double)ND)));
  }
}

extern "C" void kernel_launch(void* const* d_in, const int* in_sizes, int n_in,
                              void* d_out, int out_size, void* d_ws, size_t ws_size,
                              hipStream_t stream) {
  const float* z  = (const float*)d_in[0];
  const float* cb = (const float*)d_in[1];
  float* out = (float*)d_out;

  unsigned short* whi = (unsigned short*)d_ws;                 // 2 MB
  unsigned short* wlo = whi + (size_t)NL * NK * ND;            // 2 MB
  float* c2w = (float*)(wlo + (size_t)NL * NK * ND);           // 16 KB

  // zero the loss slot (harness poisons d_out with 0xAA)
  hipMemsetAsync((void*)(out + (size_t)NB * ND + (size_t)NB * NL), 0,
                 sizeof(float), stream);

  prep_split<<<dim3(4096), dim3(256), 0, stream>>>(cb, whi, wlo);
  prep_c2<<<dim3(4096), dim3(64), 0, stream>>>(cb, c2w);

  const size_t shmem = 72192;
  hipFuncSetAttribute((const void*)rvq_main,
                      hipFuncAttributeMaxDynamicSharedMemorySize, (int)shmem);
  rvq_main<<<dim3(NBLK), dim3(256), shmem, stream>>>(z, cb, whi, wlo, c2w, out);
}

// Round 9
// 1074.154 us; speedup vs baseline: 1.5858x; 1.4605x over previous
//
#include <hip/hip_runtime.h>

// ResidualVQ on MI355X (gfx950). ROUND 13: halve per-wave state -> 16 waves/CU.
// z: [65536,256] f32; codebooks: [4,1024,256] f32.
// Outputs (flat f32): z_q [65536*256], codes-as-float [65536*4], loss [1].
//
// R4-R12 isolated every lever at fixed ~8 waves/CU: staging (+9%), phases
// (flat), traffic/2 (worse), spill-removal @2 waves/SIMD (worse), no-barriers
// (worse). Invariant: all pipes <=25%, dur ~1.1-1.7ms -> latency-bound with
// too few waves, and occupancy was ALWAYS voided by VGPR: 32 rows/wave needs
// 128 VGPR of fragments alone (natural 236). R13 shrinks per-wave state:
// 16 rows/wave -> fragments 64 VGPR, natural ~120-130 -> fits the arg2 cap
// (128) with no spill -> 4 waves/SIMD legal. CHUNK=16 -> LDS 38.1KB -> 4
// blocks/CU x 4 waves = 16 waves/CU (2x every prior round). Grid 1024 blocks
// (MROWS=64). Per-row screen math bit-identical to the verified kernels
// (same ladder per stripe, same accum order, same top-2/merge/rescan).

#define NB 65536
#define ND 256
#define NK 1024
#define NL 4
#define MROWS 64
#define NBLK (NB / MROWS)      // 1024
#define CHUNK 16               // codes per LDS chunk (double-buffered)
#define NCH (NK / CHUNK)       // 64
#define FLAG_MARGIN 1e-3f

typedef __attribute__((ext_vector_type(8))) short short8;
typedef __attribute__((ext_vector_type(4))) float f32x4;
typedef const __attribute__((address_space(1))) unsigned int gu32;
typedef __attribute__((address_space(3))) unsigned int lu32;

#define MFMA __builtin_amdgcn_mfma_f32_16x16x32_bf16

__device__ inline unsigned short f2bf(float x) {
  unsigned u = __float_as_uint(x);
  u = u + 0x7FFFu + ((u >> 16) & 1u);        // RNE to bf16 (inputs are finite)
  return (unsigned short)(u >> 16);
}
__device__ inline float bf2f(unsigned short h) {
  return __uint_as_float(((unsigned)h) << 16);
}

// ---- numpy-bit-exact fp32 kernels (R3-proven) ----
__device__ float np_sum256_sq(const float* __restrict__ a) {
#pragma clang fp contract(off)
  float out[2];
  for (int h = 0; h < 2; ++h) {
    const float* p = a + 128 * h;
    float r[8];
    for (int j = 0; j < 8; ++j) r[j] = p[j] * p[j];
    for (int i = 8; i < 128; i += 8)
      for (int j = 0; j < 8; ++j) r[j] += p[i + j] * p[i + j];
    out[h] = ((r[0] + r[1]) + (r[2] + r[3])) + ((r[4] + r[5]) + (r[6] + r[7]));
  }
  return out[0] + out[1];
}
__device__ float np_einsum256(const float* __restrict__ r,
                              const float* __restrict__ c) {
#pragma clang fp contract(off)
  float e[4] = {0.f, 0.f, 0.f, 0.f};
  for (int d = 0; d < 256; d += 4) {
    e[0] += r[d + 0] * c[d + 0];
    e[1] += r[d + 1] * c[d + 1];
    e[2] += r[d + 2] * c[d + 2];
    e[3] += r[d + 3] * c[d + 3];
  }
  return (e[0] + e[1]) + (e[2] + e[3]);
}
__device__ float np_dist(const float* __restrict__ resrow,
                         const float* __restrict__ crow, float r2) {
#pragma clang fp contract(off)
  float E = np_einsum256(resrow, crow);
  float c2 = np_sum256_sq(crow);
  float t1 = r2 - 2.0f * E;
  return t1 + c2;
}

// ---- prep: split codebook into bf16 hi/lo, compute c2 ----
__global__ void prep_split(const float* __restrict__ cb,
                           unsigned short* __restrict__ whi,
                           unsigned short* __restrict__ wlo) {
  int i = blockIdx.x * 256 + threadIdx.x;   // 4096 blocks cover 1,048,576
  float c = cb[i];
  unsigned short h = f2bf(c);
  whi[i] = h;
  wlo[i] = f2bf(c - bf2f(h));
}
__global__ void prep_c2(const float* __restrict__ cb, float* __restrict__ c2) {
  int k = blockIdx.x;                        // 4096 codes total
  int lane = threadIdx.x;                    // 64
  const float* p = cb + (size_t)k * ND + lane * 4;
  double s = (double)p[0]*p[0] + (double)p[1]*p[1]
           + (double)p[2]*p[2] + (double)p[3]*p[3];
  for (int off = 32; off >= 1; off >>= 1) s += __shfl_down(s, off);
  if (lane == 0) c2[k] = (float)s;
}

// LDS map (38144 B):
//  bufA: @0      16384  (hi rows 0..15 x 512B @0; lo @8192) XOR-swizzled
//  bufB: @16384  16384
//  c2s:  @32768  4096   float[1024]
//  selh: @36864  1024   int[64*4]
//  flags:@37888  256    int[64]
// overlays inside bufA (phase-disjoint, DMA drained, barrier-separated):
//  resr: @0      1024   rescan residual (256 f32)
//  redf: @1024   1024   f32[256]
//  redk: @2048   1024   int[256]
//  lred: @0      2048   double[256] loss reduction (epilogue)

// DMA one 16-code chunk (hi+lo) into a 16KB buffer. 4 instrs/wave, 16 total.
// Linear LDS dest (wave-uniform base + lane*16); swizzle applied by
// pre-permuting the GLOBAL source column: slot scol holds gcol = scol^(row&7).
__device__ __forceinline__ void stage_chunk(
    const unsigned short* __restrict__ whi,
    const unsigned short* __restrict__ wlo,
    unsigned short* buf, int lvl, int ch, int wave, int lane) {
  const int rp = lane >> 5;          // row within the instr's row-pair
  const int scol = lane & 31;        // 16B slot within row
#pragma unroll
  for (int j = 0; j < 4; ++j) {
    const int g = wave * 4 + j;      // 0..15 instr id
    const int region = g >> 3;       // 0 = hi, 1 = lo
    const int gi = g & 7;            // row-pair index
    const int row = gi * 2 + rp;     // 0..15 code row in chunk
    const int gcol = scol ^ (row & 7);
    const unsigned short* src = (region ? wlo : whi)
        + (size_t)lvl * NK * ND + (size_t)(ch * CHUNK + row) * ND + gcol * 8;
    char* dst = (char*)buf + region * 8192 + gi * 1024;   // wave-uniform
    __builtin_amdgcn_global_load_lds((gu32*)src, (lu32*)dst, 16, 0, 0);
  }
}

__global__ __launch_bounds__(256, 2)
void rvq_main(const float* __restrict__ z, const float* __restrict__ cbf,
              const unsigned short* __restrict__ whi,
              const unsigned short* __restrict__ wlo,
              const float* __restrict__ c2w, float* __restrict__ out) {
  extern __shared__ char smem[];
  unsigned short* bufA = (unsigned short*)smem;
  unsigned short* bufB = (unsigned short*)(smem + 16384);
  float* c2s  = (float*)(smem + 32768);
  int*   selh = (int*)(smem + 36864);
  int*   flags= (int*)(smem + 37888);
  float* resr = (float*)smem;
  float* redf = (float*)(smem + 1024);
  int*   redk = (int*)(smem + 2048);
  double* lred= (double*)smem;

  const int tid  = threadIdx.x;
  const int wave = tid >> 6, lane = tid & 63;
  const int quad = lane >> 4, lx = lane & 15;
  const int blk  = blockIdx.x;

  for (int lvl = 0; lvl < NL; ++lvl) {
    __syncthreads();   // selh stable from prev level; overlays free
    // ---- stage c2 for this level ----
#pragma unroll
    for (int t = 0; t < 4; ++t)
      c2s[t * 256 + tid] = c2w[lvl * NK + t * 256 + tid];

    // ---- build A-fragments (register-resident, 16 rows/wave) ----
    short8 Ah[8], Al[8];
    {
      const int rloc = wave * 16 + lx;
      const size_t rg = (size_t)(blk * MROWS + rloc);
#pragma unroll
      for (int ks = 0; ks < 8; ++ks) {
        const int k0 = 32 * ks + quad * 8;
        const float* zp = z + rg * ND + k0;
        float4 p0 = *(const float4*)zp;
        float4 p1 = *(const float4*)(zp + 4);
        for (int l = 0; l < lvl; ++l) {
          int sel = selh[rloc * 4 + l];
          const float* cp = cbf + (size_t)(l * NK + sel) * ND + k0;
          float4 q0 = *(const float4*)cp, q1 = *(const float4*)(cp + 4);
          p0.x -= q0.x; p0.y -= q0.y; p0.z -= q0.z; p0.w -= q0.w;
          p1.x -= q1.x; p1.y -= q1.y; p1.z -= q1.z; p1.w -= q1.w;
        }
        float v0[8] = {p0.x, p0.y, p0.z, p0.w, p1.x, p1.y, p1.z, p1.w};
#pragma unroll
        for (int j = 0; j < 8; ++j) {
          unsigned short h = f2bf(v0[j]);
          Ah[ks][j] = (short)h;
          Al[ks][j] = (short)f2bf(v0[j] - bf2f(h));
        }
      }
    }

    // ---- screen: per-lane top-2 over 4 row streams ----
    float m1[4], m2[4]; int i1[4];
#pragma unroll
    for (int t = 0; t < 4; ++t) { m1[t] = 1e30f; m2[t] = 1e30f; i1[t] = 0; }

    // c2s visible + overlays done before any DMA lands in the buffers.
    // __syncthreads drains vmcnt -> manual counting below tracks DMAs only.
    __syncthreads();
    stage_chunk(whi, wlo, bufA, lvl, 0, wave, lane);
    stage_chunk(whi, wlo, bufB, lvl, 1, wave, lane);

#pragma unroll 1
    for (int ch = 0; ch < NCH; ++ch) {
      // wait for chunk ch's 4 DMAs (keep next chunk's 4 in flight).
      if (ch + 1 < NCH) asm volatile("s_waitcnt vmcnt(4)" ::: "memory");
      else              asm volatile("s_waitcnt vmcnt(0)" ::: "memory");
      __builtin_amdgcn_s_barrier();          // raw: no vmcnt drain
      __builtin_amdgcn_sched_barrier(0);     // rule 18: pin ds_reads below
      const unsigned short* bh = (ch & 1) ? bufB : bufA;
      {
        f32x4 a0a = {0,0,0,0}, a0b = {0,0,0,0};
        const int crow = lx;                          // 16 codes per chunk
        const unsigned short* bp = bh + crow * 256;   // 512B row stride
        const int xr = lx & 7;                        // crow & 7
        __builtin_amdgcn_s_setprio(1);                // T5: favor MFMA wave
#pragma unroll
        for (int ks = 0; ks < 8; ks += 2) {
          const int s0 = ((ks * 4 + quad) ^ xr) * 8;      // swizzled slot, hi
          const int s1 = ((ks * 4 + 4 + quad) ^ xr) * 8;  // odd ks
          short8 vb0 = *(const short8*)(bp + s0);
          short8 wb0 = *(const short8*)(bp + 4096 + s0);  // lo region +8KB
          short8 vb1 = *(const short8*)(bp + s1);
          short8 wb1 = *(const short8*)(bp + 4096 + s1);
          a0a = MFMA(Ah[ks], vb0, a0a, 0, 0, 0);
          a0a = MFMA(Al[ks], vb0, a0a, 0, 0, 0);
          a0a = MFMA(Ah[ks], wb0, a0a, 0, 0, 0);
          a0b = MFMA(Ah[ks + 1], vb1, a0b, 0, 0, 0);
          a0b = MFMA(Al[ks + 1], vb1, a0b, 0, 0, 0);
          a0b = MFMA(Ah[ks + 1], wb1, a0b, 0, 0, 0);
        }
        __builtin_amdgcn_s_setprio(0);
        const int kidx = ch * CHUNK + crow;
        const float c2v = c2s[kidx];
#pragma unroll
        for (int r = 0; r < 4; ++r) {
          float e = a0a[r] + a0b[r];
          float d = fmaf(-2.0f, e, c2v);
          if (d < m1[r]) { m2[r] = m1[r]; m1[r] = d; i1[r] = kidx; }
          else if (d < m2[r]) m2[r] = d;
        }
      }
      // my LDS reads retired before anyone overwrites this buffer
      asm volatile("s_waitcnt lgkmcnt(0)" ::: "memory");
      __builtin_amdgcn_s_barrier();          // raw: all waves done reading
      __builtin_amdgcn_sched_barrier(0);     // pin prefetch DMAs below barrier
      if (ch + 2 < NCH)
        stage_chunk(whi, wlo, (ch & 1) ? bufB : bufA, lvl, ch + 2, wave, lane);
    }
    // loop exit: vmcnt==0 (last iter drained), buffers free for overlays

    // ---- cross-lane top-2 merge: butterfly over the 16-lane lx group ----
    int myflag = 0;
#pragma unroll
    for (int t = 0; t < 4; ++t) {
      float a1 = m1[t], a2 = m2[t]; int ai = i1[t];
#pragma unroll
      for (int off = 1; off < 16; off <<= 1) {
        float o1 = __shfl_xor(a1, off);
        float o2 = __shfl_xor(a2, off);
        int   oi = __shfl_xor(ai, off);
        if (o1 < a1 || (o1 == a1 && oi < ai)) {
          a2 = fminf(a1, o2); a1 = o1; ai = oi;
        } else {
          a2 = fminf(a2, o1);
        }
      }
      if (lx == 0) {
        int rloc = wave * 16 + quad * 4 + t;
        selh[rloc * 4 + lvl] = ai;
        int f = (a2 - a1 <= FLAG_MARGIN) ? 1 : 0;
        flags[rloc] = f;
        myflag |= f;
      }
    }
    int anyf = __syncthreads_or(myflag);

    // ---- numpy-bit-exact full-K rescan of flagged rows (~0.1%) ----
    if (anyf) {
      for (int r = 0; r < MROWS; ++r) {
        if (flags[r]) {
          {
            float v = z[(size_t)(blk * MROWS + r) * ND + tid];
            for (int l = 0; l < lvl; ++l)
              v -= cbf[(size_t)(l * NK + selh[r * 4 + l]) * ND + tid];
            resr[tid] = v;
          }
          __syncthreads();
          float r2 = np_sum256_sq(resr);
          float bd = 1e30f; int bk = 0x7fffffff;
          for (int u = 0; u < 4; ++u) {
            int k = u * 256 + tid;
            float dd = np_dist(resr, cbf + (size_t)(lvl * NK + k) * ND, r2);
            if (dd < bd || (dd == bd && k < bk)) { bd = dd; bk = k; }
          }
          redf[tid] = bd; redk[tid] = bk;
          __syncthreads();
          if (tid == 0) {
            float gb = 1e30f; int gk = 0x7fffffff;
            for (int t2 = 0; t2 < 256; ++t2) {
              if (redf[t2] < gb || (redf[t2] == gb && redk[t2] < gk)) {
                gb = redf[t2]; gk = redk[t2];
              }
            }
            selh[r * 4 + lvl] = gk;
          }
          __syncthreads();
        }
      }
    }
  }

  // ---- epilogue: z_q = sum of selected codes (ref order), codes, loss ----
  __syncthreads();
  double lacc = 0.0;
#pragma unroll 1
  for (int it = 0; it < 16; ++it) {
    int i = it * 256 + tid;
    int row = i >> 6, dc = i & 63;
    size_t rg = (size_t)(blk * MROWS + row);
    float4 z4 = *(const float4*)(z + rg * ND + dc * 4);
    float4 q; q.x = 0.f; q.y = 0.f; q.z = 0.f; q.w = 0.f;
    for (int l = 0; l < NL; ++l) {
      int sel = selh[row * 4 + l];
      float4 c4 = *(const float4*)(cbf + (size_t)(l * NK + sel) * ND + dc * 4);
      q.x += c4.x; q.y += c4.y; q.z += c4.z; q.w += c4.w;
    }
    *(float4*)(out + rg * ND + dc * 4) = q;
    float dx = q.x - z4.x, dy = q.y - z4.y, dz = q.z - z4.z, dw = q.w - z4.w;
    lacc += (double)dx * dx + (double)dy * dy + (double)dz * dz + (double)dw * dw;
  }
  if (tid < MROWS) {
    for (int l = 0; l < NL; ++l)
      out[(size_t)NB * ND + (size_t)(blk * MROWS + tid) * NL + l] =
          (float)selh[tid * 4 + l];
  }
  __syncthreads();
  lred[tid] = lacc;
  __syncthreads();
  if (tid == 0) {
    double s = 0.0;
    for (int t = 0; t < 256; ++t) s += lred[t];
    atomicAdd(out + (size_t)NB * ND + (size_t)NB * NL,
              (float)(s / ((double)NB * (double)ND)));
  }
}

extern "C" void kernel_launch(void* const* d_in, const int* in_sizes, int n_in,
                              void* d_out, int out_size, void* d_ws, size_t ws_size,
                              hipStream_t stream) {
  const float* z  = (const float*)d_in[0];
  const float* cb = (const float*)d_in[1];
  float* out = (float*)d_out;

  unsigned short* whi = (unsigned short*)d_ws;                 // 2 MB
  unsigned short* wlo = whi + (size_t)NL * NK * ND;            // 2 MB
  float* c2w = (float*)(wlo + (size_t)NL * NK * ND);           // 16 KB

  // zero the loss slot (harness poisons d_out with 0xAA)
  hipMemsetAsync((void*)(out + (size_t)NB * ND + (size_t)NB * NL), 0,
                 sizeof(float), stream);

  prep_split<<<dim3(4096), dim3(256), 0, stream>>>(cb, whi, wlo);
  prep_c2<<<dim3(4096), dim3(64), 0, stream>>>(cb, c2w);

  const size_t shmem = 38144;
  hipFuncSetAttribute((const void*)rvq_main,
                      hipFuncAttributeMaxDynamicSharedMemorySize, (int)shmem);
  rvq_main<<<dim3(NBLK), dim3(256), shmem, stream>>>(z, cb, whi, wlo, c2w, out);
}

// Round 10
// 1043.700 us; speedup vs baseline: 1.6321x; 1.0292x over previous
//
#include <hip/hip_runtime.h>

// ResidualVQ on MI355X (gfx950). ROUND 14: one barrier per phase.
// z: [65536,256] f32; codebooks: [4,1024,256] f32.
// Outputs (flat f32): z_q [65536*256], codes-as-float [65536*4], loss [1].
//
// R13 (16 rows/wave, CHUNK=16, 4 blocks/CU by LDS) = 1074us best, but all
// pipes <=30% and per-CU wall ~10x the per-phase critical path -> the cost
// is per-phase sync convoys (2 barriers x 256 phases). R14: single-barrier
// phases. With a double buffer at prefetch depth 1, stage(ch+1) targets
// buf[(ch+1)%2] = the buffer read in phase ch-1, whose reads the phase-ch
// arrival barrier already certifies retired (lgkmcnt(0)+sched_barrier
// BEFORE the barrier); and since each wave does vmcnt(0) BEFORE the
// barrier, the same barrier certifies all waves' stage(ch) DMAs landed.
// Barriers halve (512->256/block); slack unchanged (stage issued right
// after the barrier, consumed one full phase later). LDS map, swizzle,
// ladder, merge, rescan, epilogue byte-identical to R13 (harness-verified).

#define NB 65536
#define ND 256
#define NK 1024
#define NL 4
#define MROWS 64
#define NBLK (NB / MROWS)      // 1024
#define CHUNK 16               // codes per LDS chunk (double-buffered)
#define NCH (NK / CHUNK)       // 64
#define FLAG_MARGIN 1e-3f

typedef __attribute__((ext_vector_type(8))) short short8;
typedef __attribute__((ext_vector_type(4))) float f32x4;
typedef const __attribute__((address_space(1))) unsigned int gu32;
typedef __attribute__((address_space(3))) unsigned int lu32;

#define MFMA __builtin_amdgcn_mfma_f32_16x16x32_bf16

__device__ inline unsigned short f2bf(float x) {
  unsigned u = __float_as_uint(x);
  u = u + 0x7FFFu + ((u >> 16) & 1u);        // RNE to bf16 (inputs are finite)
  return (unsigned short)(u >> 16);
}
__device__ inline float bf2f(unsigned short h) {
  return __uint_as_float(((unsigned)h) << 16);
}

// ---- numpy-bit-exact fp32 kernels (R3-proven) ----
__device__ float np_sum256_sq(const float* __restrict__ a) {
#pragma clang fp contract(off)
  float out[2];
  for (int h = 0; h < 2; ++h) {
    const float* p = a + 128 * h;
    float r[8];
    for (int j = 0; j < 8; ++j) r[j] = p[j] * p[j];
    for (int i = 8; i < 128; i += 8)
      for (int j = 0; j < 8; ++j) r[j] += p[i + j] * p[i + j];
    out[h] = ((r[0] + r[1]) + (r[2] + r[3])) + ((r[4] + r[5]) + (r[6] + r[7]));
  }
  return out[0] + out[1];
}
__device__ float np_einsum256(const float* __restrict__ r,
                              const float* __restrict__ c) {
#pragma clang fp contract(off)
  float e[4] = {0.f, 0.f, 0.f, 0.f};
  for (int d = 0; d < 256; d += 4) {
    e[0] += r[d + 0] * c[d + 0];
    e[1] += r[d + 1] * c[d + 1];
    e[2] += r[d + 2] * c[d + 2];
    e[3] += r[d + 3] * c[d + 3];
  }
  return (e[0] + e[1]) + (e[2] + e[3]);
}
__device__ float np_dist(const float* __restrict__ resrow,
                         const float* __restrict__ crow, float r2) {
#pragma clang fp contract(off)
  float E = np_einsum256(resrow, crow);
  float c2 = np_sum256_sq(crow);
  float t1 = r2 - 2.0f * E;
  return t1 + c2;
}

// ---- prep: split codebook into bf16 hi/lo, compute c2 ----
__global__ void prep_split(const float* __restrict__ cb,
                           unsigned short* __restrict__ whi,
                           unsigned short* __restrict__ wlo) {
  int i = blockIdx.x * 256 + threadIdx.x;   // 4096 blocks cover 1,048,576
  float c = cb[i];
  unsigned short h = f2bf(c);
  whi[i] = h;
  wlo[i] = f2bf(c - bf2f(h));
}
__global__ void prep_c2(const float* __restrict__ cb, float* __restrict__ c2) {
  int k = blockIdx.x;                        // 4096 codes total
  int lane = threadIdx.x;                    // 64
  const float* p = cb + (size_t)k * ND + lane * 4;
  double s = (double)p[0]*p[0] + (double)p[1]*p[1]
           + (double)p[2]*p[2] + (double)p[3]*p[3];
  for (int off = 32; off >= 1; off >>= 1) s += __shfl_down(s, off);
  if (lane == 0) c2[k] = (float)s;
}

// LDS map (38144 B):
//  bufA: @0      16384  (hi rows 0..15 x 512B @0; lo @8192) XOR-swizzled
//  bufB: @16384  16384
//  c2s:  @32768  4096   float[1024]
//  selh: @36864  1024   int[64*4]
//  flags:@37888  256    int[64]
// overlays inside bufA (phase-disjoint, DMA drained, barrier-separated):
//  resr: @0      1024   rescan residual (256 f32)
//  redf: @1024   1024   f32[256]
//  redk: @2048   1024   int[256]
//  lred: @0      2048   double[256] loss reduction (epilogue)

// DMA one 16-code chunk (hi+lo) into a 16KB buffer. 4 instrs/wave, 16 total.
// Linear LDS dest (wave-uniform base + lane*16); swizzle applied by
// pre-permuting the GLOBAL source column: slot scol holds gcol = scol^(row&7).
__device__ __forceinline__ void stage_chunk(
    const unsigned short* __restrict__ whi,
    const unsigned short* __restrict__ wlo,
    unsigned short* buf, int lvl, int ch, int wave, int lane) {
  const int rp = lane >> 5;          // row within the instr's row-pair
  const int scol = lane & 31;        // 16B slot within row
#pragma unroll
  for (int j = 0; j < 4; ++j) {
    const int g = wave * 4 + j;      // 0..15 instr id
    const int region = g >> 3;       // 0 = hi, 1 = lo
    const int gi = g & 7;            // row-pair index
    const int row = gi * 2 + rp;     // 0..15 code row in chunk
    const int gcol = scol ^ (row & 7);
    const unsigned short* src = (region ? wlo : whi)
        + (size_t)lvl * NK * ND + (size_t)(ch * CHUNK + row) * ND + gcol * 8;
    char* dst = (char*)buf + region * 8192 + gi * 1024;   // wave-uniform
    __builtin_amdgcn_global_load_lds((gu32*)src, (lu32*)dst, 16, 0, 0);
  }
}

__global__ __launch_bounds__(256, 2)
void rvq_main(const float* __restrict__ z, const float* __restrict__ cbf,
              const unsigned short* __restrict__ whi,
              const unsigned short* __restrict__ wlo,
              const float* __restrict__ c2w, float* __restrict__ out) {
  extern __shared__ char smem[];
  unsigned short* bufA = (unsigned short*)smem;
  unsigned short* bufB = (unsigned short*)(smem + 16384);
  float* c2s  = (float*)(smem + 32768);
  int*   selh = (int*)(smem + 36864);
  int*   flags= (int*)(smem + 37888);
  float* resr = (float*)smem;
  float* redf = (float*)(smem + 1024);
  int*   redk = (int*)(smem + 2048);
  double* lred= (double*)smem;

  const int tid  = threadIdx.x;
  const int wave = tid >> 6, lane = tid & 63;
  const int quad = lane >> 4, lx = lane & 15;
  const int blk  = blockIdx.x;

  for (int lvl = 0; lvl < NL; ++lvl) {
    __syncthreads();   // selh stable from prev level; overlays free
    // ---- stage c2 for this level ----
#pragma unroll
    for (int t = 0; t < 4; ++t)
      c2s[t * 256 + tid] = c2w[lvl * NK + t * 256 + tid];

    // ---- build A-fragments (register-resident, 16 rows/wave) ----
    short8 Ah[8], Al[8];
    {
      const int rloc = wave * 16 + lx;
      const size_t rg = (size_t)(blk * MROWS + rloc);
#pragma unroll
      for (int ks = 0; ks < 8; ++ks) {
        const int k0 = 32 * ks + quad * 8;
        const float* zp = z + rg * ND + k0;
        float4 p0 = *(const float4*)zp;
        float4 p1 = *(const float4*)(zp + 4);
        for (int l = 0; l < lvl; ++l) {
          int sel = selh[rloc * 4 + l];
          const float* cp = cbf + (size_t)(l * NK + sel) * ND + k0;
          float4 q0 = *(const float4*)cp, q1 = *(const float4*)(cp + 4);
          p0.x -= q0.x; p0.y -= q0.y; p0.z -= q0.z; p0.w -= q0.w;
          p1.x -= q1.x; p1.y -= q1.y; p1.z -= q1.z; p1.w -= q1.w;
        }
        float v0[8] = {p0.x, p0.y, p0.z, p0.w, p1.x, p1.y, p1.z, p1.w};
#pragma unroll
        for (int j = 0; j < 8; ++j) {
          unsigned short h = f2bf(v0[j]);
          Ah[ks][j] = (short)h;
          Al[ks][j] = (short)f2bf(v0[j] - bf2f(h));
        }
      }
    }

    // ---- screen: per-lane top-2 over 4 row streams ----
    float m1[4], m2[4]; int i1[4];
#pragma unroll
    for (int t = 0; t < 4; ++t) { m1[t] = 1e30f; m2[t] = 1e30f; i1[t] = 0; }

    // c2s visible + overlays done before any DMA lands in the buffers.
    // __syncthreads drains vmcnt -> counting below tracks staging DMAs only.
    __syncthreads();
    stage_chunk(whi, wlo, bufA, lvl, 0, wave, lane);

    // Single-barrier phases: at the top of phase ch,
    //  (1) lgkmcnt(0)+sched_barrier: my phase-(ch-1) LDS reads retired;
    //  (2) vmcnt(0): my stage(ch) DMAs landed (nothing younger in flight);
    //  (3) s_barrier: everyone did (1)+(2) -> buf[ch%2] fully staged AND
    //      buf[(ch+1)%2] (read in ch-1) free to overwrite;
    //  (4) issue stage(ch+1) into buf[(ch+1)%2], then compute buf[ch%2].
#pragma unroll 1
    for (int ch = 0; ch < NCH; ++ch) {
      asm volatile("s_waitcnt lgkmcnt(0)" ::: "memory");
      __builtin_amdgcn_sched_barrier(0);
      asm volatile("s_waitcnt vmcnt(0)" ::: "memory");
      __builtin_amdgcn_s_barrier();
      __builtin_amdgcn_sched_barrier(0);     // rule 18: pin reads/DMAs below
      if (ch + 1 < NCH)
        stage_chunk(whi, wlo, (ch & 1) ? bufA : bufB, lvl, ch + 1, wave, lane);
      const unsigned short* bh = (ch & 1) ? bufB : bufA;
      {
        f32x4 a0a = {0,0,0,0}, a0b = {0,0,0,0};
        const int crow = lx;                          // 16 codes per chunk
        const unsigned short* bp = bh + crow * 256;   // 512B row stride
        const int xr = lx & 7;                        // crow & 7
        __builtin_amdgcn_s_setprio(1);                // T5: favor MFMA wave
#pragma unroll
        for (int ks = 0; ks < 8; ks += 2) {
          const int s0 = ((ks * 4 + quad) ^ xr) * 8;      // swizzled slot, hi
          const int s1 = ((ks * 4 + 4 + quad) ^ xr) * 8;  // odd ks
          short8 vb0 = *(const short8*)(bp + s0);
          short8 wb0 = *(const short8*)(bp + 4096 + s0);  // lo region +8KB
          short8 vb1 = *(const short8*)(bp + s1);
          short8 wb1 = *(const short8*)(bp + 4096 + s1);
          a0a = MFMA(Ah[ks], vb0, a0a, 0, 0, 0);
          a0a = MFMA(Al[ks], vb0, a0a, 0, 0, 0);
          a0a = MFMA(Ah[ks], wb0, a0a, 0, 0, 0);
          a0b = MFMA(Ah[ks + 1], vb1, a0b, 0, 0, 0);
          a0b = MFMA(Al[ks + 1], vb1, a0b, 0, 0, 0);
          a0b = MFMA(Ah[ks + 1], wb1, a0b, 0, 0, 0);
        }
        __builtin_amdgcn_s_setprio(0);
        const int kidx = ch * CHUNK + crow;
        const float c2v = c2s[kidx];
#pragma unroll
        for (int r = 0; r < 4; ++r) {
          float e = a0a[r] + a0b[r];
          float d = fmaf(-2.0f, e, c2v);
          if (d < m1[r]) { m2[r] = m1[r]; m1[r] = d; i1[r] = kidx; }
          else if (d < m2[r]) m2[r] = d;
        }
      }
      // no second barrier: next phase's arrival barrier certifies these
      // reads retired (via its lgkmcnt(0)) before this buffer is re-staged.
    }
    // loop exit: vmcnt==0 (last stage waited at ch=NCH-1), buffers free

    // ---- cross-lane top-2 merge: butterfly over the 16-lane lx group ----
    int myflag = 0;
#pragma unroll
    for (int t = 0; t < 4; ++t) {
      float a1 = m1[t], a2 = m2[t]; int ai = i1[t];
#pragma unroll
      for (int off = 1; off < 16; off <<= 1) {
        float o1 = __shfl_xor(a1, off);
        float o2 = __shfl_xor(a2, off);
        int   oi = __shfl_xor(ai, off);
        if (o1 < a1 || (o1 == a1 && oi < ai)) {
          a2 = fminf(a1, o2); a1 = o1; ai = oi;
        } else {
          a2 = fminf(a2, o1);
        }
      }
      if (lx == 0) {
        int rloc = wave * 16 + quad * 4 + t;
        selh[rloc * 4 + lvl] = ai;
        int f = (a2 - a1 <= FLAG_MARGIN) ? 1 : 0;
        flags[rloc] = f;
        myflag |= f;
      }
    }
    int anyf = __syncthreads_or(myflag);

    // ---- numpy-bit-exact full-K rescan of flagged rows (~0.1%) ----
    if (anyf) {
      for (int r = 0; r < MROWS; ++r) {
        if (flags[r]) {
          {
            float v = z[(size_t)(blk * MROWS + r) * ND + tid];
            for (int l = 0; l < lvl; ++l)
              v -= cbf[(size_t)(l * NK + selh[r * 4 + l]) * ND + tid];
            resr[tid] = v;
          }
          __syncthreads();
          float r2 = np_sum256_sq(resr);
          float bd = 1e30f; int bk = 0x7fffffff;
          for (int u = 0; u < 4; ++u) {
            int k = u * 256 + tid;
            float dd = np_dist(resr, cbf + (size_t)(lvl * NK + k) * ND, r2);
            if (dd < bd || (dd == bd && k < bk)) { bd = dd; bk = k; }
          }
          redf[tid] = bd; redk[tid] = bk;
          __syncthreads();
          if (tid == 0) {
            float gb = 1e30f; int gk = 0x7fffffff;
            for (int t2 = 0; t2 < 256; ++t2) {
              if (redf[t2] < gb || (redf[t2] == gb && redk[t2] < gk)) {
                gb = redf[t2]; gk = redk[t2];
              }
            }
            selh[r * 4 + lvl] = gk;
          }
          __syncthreads();
        }
      }
    }
  }

  // ---- epilogue: z_q = sum of selected codes (ref order), codes, loss ----
  __syncthreads();
  double lacc = 0.0;
#pragma unroll 1
  for (int it = 0; it < 16; ++it) {
    int i = it * 256 + tid;
    int row = i >> 6, dc = i & 63;
    size_t rg = (size_t)(blk * MROWS + row);
    float4 z4 = *(const float4*)(z + rg * ND + dc * 4);
    float4 q; q.x = 0.f; q.y = 0.f; q.z = 0.f; q.w = 0.f;
    for (int l = 0; l < NL; ++l) {
      int sel = selh[row * 4 + l];
      float4 c4 = *(const float4*)(cbf + (size_t)(l * NK + sel) * ND + dc * 4);
      q.x += c4.x; q.y += c4.y; q.z += c4.z; q.w += c4.w;
    }
    *(float4*)(out + rg * ND + dc * 4) = q;
    float dx = q.x - z4.x, dy = q.y - z4.y, dz = q.z - z4.z, dw = q.w - z4.w;
    lacc += (double)dx * dx + (double)dy * dy + (double)dz * dz + (double)dw * dw;
  }
  if (tid < MROWS) {
    for (int l = 0; l < NL; ++l)
      out[(size_t)NB * ND + (size_t)(blk * MROWS + tid) * NL + l] =
          (float)selh[tid * 4 + l];
  }
  __syncthreads();
  lred[tid] = lacc;
  __syncthreads();
  if (tid == 0) {
    double s = 0.0;
    for (int t = 0; t < 256; ++t) s += lred[t];
    atomicAdd(out + (size_t)NB * ND + (size_t)NB * NL,
              (float)(s / ((double)NB * (double)ND)));
  }
}

extern "C" void kernel_launch(void* const* d_in, const int* in_sizes, int n_in,
                              void* d_out, int out_size, void* d_ws, size_t ws_size,
                              hipStream_t stream) {
  const float* z  = (const float*)d_in[0];
  const float* cb = (const float*)d_in[1];
  float* out = (float*)d_out;

  unsigned short* whi = (unsigned short*)d_ws;                 // 2 MB
  unsigned short* wlo = whi + (size_t)NL * NK * ND;            // 2 MB
  float* c2w = (float*)(wlo + (size_t)NL * NK * ND);           // 16 KB

  // zero the loss slot (harness poisons d_out with 0xAA)
  hipMemsetAsync((void*)(out + (size_t)NB * ND + (size_t)NB * NL), 0,
                 sizeof(float), stream);

  prep_split<<<dim3(4096), dim3(256), 0, stream>>>(cb, whi, wlo);
  prep_c2<<<dim3(4096), dim3(64), 0, stream>>>(cb, c2w);

  const size_t shmem = 38144;
  hipFuncSetAttribute((const void*)rvq_main,
                      hipFuncAttributeMaxDynamicSharedMemorySize, (int)shmem);
  rvq_main<<<dim3(NBLK), dim3(256), shmem, stream>>>(z, cb, whi, wlo, c2w, out);
}